// Round 4
// baseline (464.409 us; speedup 1.0000x reference)
//
#include <hip/hip_runtime.h>

#define Bc   64
#define Cc   256
#define Nn   2304
#define DFFf 512
#define Mm   64
#define NTILE 64
#define NTB   36   // 2304/64

typedef __bf16 bf16_t;
typedef __bf16 bf16x8 __attribute__((ext_vector_type(8)));
typedef __bf16 bf16x4 __attribute__((ext_vector_type(4)));
typedef float  f32x4  __attribute__((ext_vector_type(4)));
typedef float  f32x2  __attribute__((ext_vector_type(2)));

__device__ __forceinline__ bf16_t cvt(float f) { return (bf16_t)f; }

__device__ __forceinline__ f32x4 mfma16(bf16x8 a, bf16x8 b, f32x4 c) {
    return __builtin_amdgcn_mfma_f32_16x16x32_bf16(a, b, c, 0, 0, 0);
}

// ---------------------------------------------------------------------------
// K/V precompute (fp32): K[c][m] = wk[c,:]·bcw[m,:] + bk[c]   (unchanged)
// ---------------------------------------------------------------------------
__global__ void kv_kernel(const float* __restrict__ wk, const float* __restrict__ bk,
                          const float* __restrict__ wv, const float* __restrict__ bv,
                          const float* __restrict__ bcw,
                          float* __restrict__ Kout, float* __restrict__ Vout) {
    int c = blockIdx.x;      // 256
    int m = threadIdx.x;     // 64
    const float* wkr = wk + c * Cc;
    const float* wvr = wv + c * Cc;
    const float* br  = bcw + m * Cc;
    float aK = 0.f, aV = 0.f;
    #pragma unroll 8
    for (int i = 0; i < Cc; ++i) {
        float bcv = br[i];
        aK = fmaf(wkr[i], bcv, aK);
        aV = fmaf(wvr[i], bcv, aV);
    }
    Kout[c * Mm + m] = aK + bk[c];
    Vout[c * Mm + m] = aV + bv[c];
}

// ---------------------------------------------------------------------------
// Pack weights into MFMA A-fragment order (bf16).  (identical to round 3)
// ---------------------------------------------------------------------------
__global__ void pack_kernel(const float* __restrict__ wq, const float* __restrict__ bq,
                            const float* __restrict__ wm, const float* __restrict__ w1,
                            const float* __restrict__ w2,
                            const float* __restrict__ Kf32, const float* __restrict__ Vf32,
                            bf16_t* __restrict__ wqf, bf16_t* __restrict__ wmf,
                            bf16_t* __restrict__ w1f, bf16_t* __restrict__ w2f,
                            bf16_t* __restrict__ Kf, bf16_t* __restrict__ Vf,
                            float* __restrict__ bqp) {
    int idx = blockIdx.x * 256 + threadIdx.x;
    if (idx < 65536) {                       // wqf: 16rt x 8ks, d-permuted rows
        int e = idx;
        int j = e & 7, lane = (e >> 3) & 63, rs = e >> 9;
        int ks = rs & 7, rt = rs >> 3;
        int rho = lane & 15;                      // frag row in tile
        int h = rt >> 1, rtl = rt & 1;
        int d = 8 * (rho >> 2) + 4 * rtl + (rho & 3);   // d-permutation
        int k  = ks * 32 + (lane >> 4) * 8 + j;
        int c  = d * 8 + h;                       // feature channel for (d,h)
        wqf[e] = cvt(wq[c * 256 + k]);
    } else if (idx < 131072) {               // wmf: col-permuted
        int e = idx - 65536;
        int j = e & 7, lane = (e >> 3) & 63, rs = e >> 9;
        int ks = rs & 7, rt = rs >> 3;
        int o = rt * 16 + (lane & 15);
        int k = ks * 32 + (lane >> 4) * 8 + j;    // hd
        int c = (k & 31) * 8 + (k >> 5);
        wmf[e] = cvt(wm[o * 256 + c]);
    } else if (idx < 262144) {               // w1f: 32rt x 8ks plain
        int e = idx - 131072;
        int j = e & 7, lane = (e >> 3) & 63, rs = e >> 9;
        int ks = rs & 7, rt = rs >> 3;
        w1f[e] = cvt(w1[(rt * 16 + (lane & 15)) * 256 + ks * 32 + (lane >> 4) * 8 + j]);
    } else if (idx < 393216) {               // w2f: 16rt x 16ks plain (K=512)
        int e = idx - 262144;
        int j = e & 7, lane = (e >> 3) & 63, rs = e >> 9;
        int ks = rs & 15, rt = rs >> 4;
        w2f[e] = cvt(w2[(rt * 16 + (lane & 15)) * 512 + ks * 32 + (lane >> 4) * 8 + j]);
    } else if (idx < 409600) {               // Kf: [h][mt] A-frag A[m-perm][d]
        int e = idx - 393216;
        int j = e & 7, lane = (e >> 3) & 63, hm = e >> 9;
        int mt = hm & 3, h = hm >> 2;
        int lid = lane & 15;
        int d = (lane >> 4) * 8 + j;
        int m = 32 * (mt >> 1) + 4 * (mt & 1) + 8 * (lid >> 2) + (lid & 3);
        Kf[e] = cvt(Kf32[(d * 8 + h) * 64 + m]);
    } else if (idx < 425984) {               // Vf: [h][rt][ks] A-frag A[d][m]
        int e = idx - 409600;
        int j = e & 7, lane = (e >> 3) & 63, x = e >> 9;
        int ks = x & 1, rt = (x >> 1) & 1, h = x >> 2;
        int d = rt * 16 + (lane & 15), m = ks * 32 + (lane >> 4) * 8 + j;
        Vf[e] = cvt(Vf32[(d * 8 + h) * 64 + m]);
    } else if (idx < 426240) {               // bqp (hd-ordered)
        int op = idx - 425984;
        int c = (op & 31) * 8 + (op >> 5);
        bqp[op] = bq[c];
    }
}

// ---------------------------------------------------------------------------
// Fused SFTA. 1024 threads = 16 waves; wave w owns out-channel tile rt = w.
// 2 blocks/CU x 16 waves = 32 waves/CU (100% occupancy cap).
// Round-4 changes: (a) coalesced n-minor staging restored (256 B contiguous
// per 16-lane group); (b) attention register-scoped to fit the 64-VGPR budget
// of launch_bounds(1024,8): only K frags persist, V frags loaded after
// softmax when score registers are dead.  No scratch expected.
// ---------------------------------------------------------------------------
__global__ __launch_bounds__(1024, 8) void sfta_mfma(
    const float* __restrict__ feat,
    const bf16_t* __restrict__ wqf, const float* __restrict__ bqp,
    const bf16_t* __restrict__ wmf, const float* __restrict__ bm,
    const bf16_t* __restrict__ w1f, const float* __restrict__ b1,
    const bf16_t* __restrict__ w2f, const float* __restrict__ b2,
    const bf16_t* __restrict__ Kf,  const bf16_t* __restrict__ Vf,
    const float* __restrict__ gam,  const float* __restrict__ bet,
    float* __restrict__ out) {
    __shared__ __align__(16) bf16_t sFeat[64 * 264];   // [n][c] feat -> rescaled
    __shared__ __align__(16) bf16_t sQX[64 * 264];     // [n][hd]: q -> x -> h1
    __shared__ float sRed[3][64][18];                  // cross-wave row partials

    const int t    = threadIdx.x;
    const int wid  = t >> 6;          // 0..15: rt owner
    const int lane = t & 63;
    const int quad = lane >> 4;
    const int lid  = lane & 15;
    const int h    = wid >> 1;        // head for q/attn phases
    const int rtl  = wid & 1;         // d-half within head
    const int b    = blockIdx.y;
    const int n0   = blockIdx.x * NTILE;
    const size_t baseF = (size_t)b * Cc * Nn + n0;

    // ---- stage feature tile: [c][n] fp32 -> LDS [n][c] bf16 (coalesced) ----
    {
        int cb = t >> 4;            // 0..63 (16-lane groups share a channel)
        int nb = (t & 15) * 4;      // 0..60 (n-minor: 256 B contiguous reads)
        #pragma unroll
        for (int i = 0; i < 4; ++i) {
            int c = i * 64 + cb;
            const float4 f4 = *(const float4*)(feat + baseF + (size_t)c * Nn + nb);
            sFeat[(nb + 0) * 264 + c] = cvt(f4.x);
            sFeat[(nb + 1) * 264 + c] = cvt(f4.y);
            sFeat[(nb + 2) * 264 + c] = cvt(f4.z);
            sFeat[(nb + 3) * 264 + c] = cvt(f4.w);
        }
    }
    __syncthreads();

    // ---- Q projection: wave computes rt=wid (16 q-channels, d-permuted) ----
    {
        f32x4 qacc[4];
        #pragma unroll
        for (int nt = 0; nt < 4; ++nt) qacc[nt] = (f32x4){0.f, 0.f, 0.f, 0.f};
        #pragma unroll
        for (int ks = 0; ks < 8; ++ks) {
            bf16x8 a = *(const bf16x8*)(wqf + ((wid * 8 + ks) * 64 + lane) * 8);
            #pragma unroll
            for (int nt = 0; nt < 4; ++nt) {
                bf16x8 bfr = *(const bf16x8*)(sFeat + (nt * 16 + lid) * 264 + ks * 32 + quad * 8);
                qacc[nt] = mfma16(a, bfr, qacc[nt]);
            }
        }
        const float4 qb = *(const float4*)(bqp + h * 32 + quad * 8 + rtl * 4);
        #pragma unroll
        for (int nt = 0; nt < 4; ++nt) {
            bf16x4 o;
            o[0] = cvt(qacc[nt][0] + qb.x);
            o[1] = cvt(qacc[nt][1] + qb.y);
            o[2] = cvt(qacc[nt][2] + qb.z);
            o[3] = cvt(qacc[nt][3] + qb.w);
            *(bf16x4*)(sQX + (nt * 16 + lid) * 264 + h * 32 + quad * 8 + rtl * 4) = o;
        }
    }
    __syncthreads();   // q halves combined across wave pairs

    // ---- attention: wave handles (head=h, g = rtl*2 + u) for u=0..1 ----
    {
        bf16x8 kb[4];                 // K frags persist across both g-groups
        #pragma unroll
        for (int mt = 0; mt < 4; ++mt)
            kb[mt] = *(const bf16x8*)(Kf + ((h * 4 + mt) * 64 + lane) * 8);
        const float scl2 = 0.17677669529663687f * 1.4426950408889634f; // /sqrt32 * log2e
        #pragma unroll 1
        for (int u = 0; u < 2; ++u) {
            int g = rtl * 2 + u;
            float p[16];
            {   // scores in a tight scope so sc dies before V loads
                bf16x8 aq = *(const bf16x8*)(sQX + (g * 16 + lid) * 264 + h * 32 + quad * 8);
                #pragma unroll
                for (int mt = 0; mt < 4; ++mt) {
                    f32x4 z = {0.f, 0.f, 0.f, 0.f};
                    f32x4 sc = mfma16(kb[mt], aq, z);      // D[m-perm][n=lid]
                    #pragma unroll
                    for (int r = 0; r < 4; ++r) p[mt * 4 + r] = sc[r] * scl2;
                }
            }
            float mx = p[0];
            #pragma unroll
            for (int i = 1; i < 16; ++i) mx = fmaxf(mx, p[i]);
            mx = fmaxf(mx, __shfl_xor(mx, 16));
            mx = fmaxf(mx, __shfl_xor(mx, 32));
            float s = 0.f;
            #pragma unroll
            for (int i = 0; i < 16; ++i) { p[i] = exp2f(p[i] - mx); s += p[i]; }
            s += __shfl_xor(s, 16);
            s += __shfl_xor(s, 32);
            float inv = 1.f / s;
            bf16x8 bp[2];                            // PV B-frag, in-lane pack
            #pragma unroll
            for (int ks = 0; ks < 2; ++ks)
                #pragma unroll
                for (int jj = 0; jj < 8; ++jj)
                    bp[ks][jj] = cvt(p[(2 * ks + (jj >> 2)) * 4 + (jj & 3)] * inv);
            #pragma unroll
            for (int rv = 0; rv < 2; ++rv) {         // PV: D[d][n]; V frags transient
                f32x4 x = {0.f, 0.f, 0.f, 0.f};
                bf16x8 va0 = *(const bf16x8*)(Vf + ((h * 4 + rv * 2 + 0) * 64 + lane) * 8);
                x = mfma16(va0, bp[0], x);
                bf16x8 va1 = *(const bf16x8*)(Vf + ((h * 4 + rv * 2 + 1) * 64 + lane) * 8);
                x = mfma16(va1, bp[1], x);
                bf16x4 o;
                #pragma unroll
                for (int r = 0; r < 4; ++r) o[r] = cvt(x[r]);
                *(bf16x4*)(sQX + (g * 16 + lid) * 264 + h * 32 + rv * 16 + quad * 4) = o;
            }
        }
    }
    __syncthreads();   // x complete across all heads

    // ---- merge GEMM (rt = wid) + cosine partials ----
    float pmf[4], pmm[4], pff[4];
    {
        f32x4 acc[4];
        #pragma unroll
        for (int nt = 0; nt < 4; ++nt) acc[nt] = (f32x4){0.f, 0.f, 0.f, 0.f};
        #pragma unroll
        for (int ks = 0; ks < 8; ++ks) {
            bf16x8 a = *(const bf16x8*)(wmf + ((wid * 8 + ks) * 64 + lane) * 8);
            #pragma unroll
            for (int nt = 0; nt < 4; ++nt) {
                bf16x8 bx = *(const bf16x8*)(sQX + (nt * 16 + lid) * 264 + ks * 32 + quad * 8);
                acc[nt] = mfma16(a, bx, acc[nt]);
            }
        }
        const float4 bmv = *(const float4*)(bm + wid * 16 + quad * 4);
        #pragma unroll
        for (int nt = 0; nt < 4; ++nt) { pmf[nt] = 0.f; pmm[nt] = 0.f; pff[nt] = 0.f; }
        #pragma unroll
        for (int nt = 0; nt < 4; ++nt) {
            bf16x4 f4 = *(const bf16x4*)(sFeat + (nt * 16 + lid) * 264 + wid * 16 + quad * 4);
            #pragma unroll
            for (int r = 0; r < 4; ++r) {
                float m = acc[nt][r] + ((const float*)&bmv)[r];
                float f = (float)f4[r];
                pmf[nt] = fmaf(m, f, pmf[nt]);
                pmm[nt] = fmaf(m, m, pmm[nt]);
                pff[nt] = fmaf(f, f, pff[nt]);
            }
        }
    }
    #pragma unroll
    for (int nt = 0; nt < 4; ++nt) {
        pmf[nt] += __shfl_xor(pmf[nt], 16); pmf[nt] += __shfl_xor(pmf[nt], 32);
        pmm[nt] += __shfl_xor(pmm[nt], 16); pmm[nt] += __shfl_xor(pmm[nt], 32);
        pff[nt] += __shfl_xor(pff[nt], 16); pff[nt] += __shfl_xor(pff[nt], 32);
    }
    if (lane < 16) {
        #pragma unroll
        for (int nt = 0; nt < 4; ++nt) {
            sRed[0][nt * 16 + lane][wid] = pmf[nt];
            sRed[1][nt * 16 + lane][wid] = pmm[nt];
            sRed[2][nt * 16 + lane][wid] = pff[nt];
        }
    }
    __syncthreads();

    // ---- rescale feat in place: row = wid*4+quad, 16 ch per lane ----
    {
        int row = wid * 4 + quad;
        float smf = 0.f, smm = 0.f, sff = 0.f;
        #pragma unroll
        for (int k2 = 0; k2 < 8; ++k2) {
            f32x2 a0 = *(const f32x2*)(&sRed[0][row][k2 * 2]);
            f32x2 a1 = *(const f32x2*)(&sRed[1][row][k2 * 2]);
            f32x2 a2 = *(const f32x2*)(&sRed[2][row][k2 * 2]);
            smf += a0[0] + a0[1];
            smm += a1[0] + a1[1];
            sff += a2[0] + a2[1];
        }
        float scale = smf / ((sqrtf(smm) + 1e-5f) * (sqrtf(sff) + 1e-5f)) + 1.f;
        bf16_t* frow = sFeat + row * 264 + lid * 16;
        #pragma unroll
        for (int i = 0; i < 2; ++i) {
            bf16x8* pp = (bf16x8*)(frow + i * 8);
            bf16x8 v = *pp;
            #pragma unroll
            for (int e = 0; e < 8; ++e) v[e] = cvt((float)v[e] * scale);
            *pp = v;
        }
    }
    __syncthreads();

    // ---- FFN: 2 chunks of 256 f-channels; wave owns 1 f-tile per chunk ----
    f32x4 acc2[4];
    #pragma unroll
    for (int nt = 0; nt < 4; ++nt) acc2[nt] = (f32x4){0.f, 0.f, 0.f, 0.f};
    #pragma unroll 1
    for (int c = 0; c < 2; ++c) {
        int rt1 = c * 16 + wid;
        {
            f32x4 a1[4];
            #pragma unroll
            for (int nt = 0; nt < 4; ++nt) a1[nt] = (f32x4){0.f, 0.f, 0.f, 0.f};
            #pragma unroll
            for (int ks = 0; ks < 8; ++ks) {
                bf16x8 a = *(const bf16x8*)(w1f + ((rt1 * 8 + ks) * 64 + lane) * 8);
                #pragma unroll
                for (int nt = 0; nt < 4; ++nt) {
                    bf16x8 bfr = *(const bf16x8*)(sFeat + (nt * 16 + lid) * 264 + ks * 32 + quad * 8);
                    a1[nt] = mfma16(a, bfr, a1[nt]);
                }
            }
            const float4 b1v = *(const float4*)(b1 + rt1 * 16 + quad * 4);
            #pragma unroll
            for (int nt = 0; nt < 4; ++nt) {
                bf16x4 o;
                o[0] = cvt(fmaxf(a1[nt][0] + b1v.x, 0.f));
                o[1] = cvt(fmaxf(a1[nt][1] + b1v.y, 0.f));
                o[2] = cvt(fmaxf(a1[nt][2] + b1v.z, 0.f));
                o[3] = cvt(fmaxf(a1[nt][3] + b1v.w, 0.f));
                *(bf16x4*)(sQX + (nt * 16 + lid) * 264 + wid * 16 + quad * 4) = o;
            }
        }
        __syncthreads();   // h1 chunk complete
        #pragma unroll
        for (int kk = 0; kk < 8; ++kk) {
            bf16x8 a = *(const bf16x8*)(w2f + ((wid * 16 + c * 8 + kk) * 64 + lane) * 8);
            #pragma unroll
            for (int nt = 0; nt < 4; ++nt) {
                bf16x8 bh = *(const bf16x8*)(sQX + (nt * 16 + lid) * 264 + kk * 32 + quad * 8);
                acc2[nt] = mfma16(a, bh, acc2[nt]);
            }
        }
        __syncthreads();   // chunk consumed; safe to overwrite sQX
    }

    // ---- residual + LayerNorm partials ----
    float ps[4] = {0.f, 0.f, 0.f, 0.f}, pq[4] = {0.f, 0.f, 0.f, 0.f};
    {
        const float4 b2v = *(const float4*)(b2 + wid * 16 + quad * 4);
        #pragma unroll
        for (int nt = 0; nt < 4; ++nt) {
            bf16x4 f4 = *(const bf16x4*)(sFeat + (nt * 16 + lid) * 264 + wid * 16 + quad * 4);
            #pragma unroll
            for (int r = 0; r < 4; ++r) {
                float v = acc2[nt][r] + ((const float*)&b2v)[r] + (float)f4[r];
                acc2[nt][r] = v;
                ps[nt] += v;
                pq[nt] = fmaf(v, v, pq[nt]);
            }
        }
    }
    #pragma unroll
    for (int nt = 0; nt < 4; ++nt) {
        ps[nt] += __shfl_xor(ps[nt], 16); ps[nt] += __shfl_xor(ps[nt], 32);
        pq[nt] += __shfl_xor(pq[nt], 16); pq[nt] += __shfl_xor(pq[nt], 32);
    }
    if (lane < 16) {
        #pragma unroll
        for (int nt = 0; nt < 4; ++nt) {
            sRed[0][nt * 16 + lane][wid] = ps[nt];
            sRed[1][nt * 16 + lane][wid] = pq[nt];
        }
    }
    __syncthreads();

    // ---- LayerNorm + store (16 channels x all 64 rows per wave) ----
    float* op = out + baseF;
    const float4 gv = *(const float4*)(gam + wid * 16 + quad * 4);
    const float4 bv = *(const float4*)(bet + wid * 16 + quad * 4);
    #pragma unroll
    for (int nt = 0; nt < 4; ++nt) {
        int row = nt * 16 + lid;
        float s = 0.f, q = 0.f;
        #pragma unroll
        for (int k2 = 0; k2 < 2; ++k2) {
            f32x2 a0 = *(const f32x2*)(&sRed[0][row][quad * 4 + k2 * 2]);
            f32x2 a1 = *(const f32x2*)(&sRed[1][row][quad * 4 + k2 * 2]);
            s += a0[0] + a0[1];
            q += a1[0] + a1[1];
        }
        s += __shfl_xor(s, 16); s += __shfl_xor(s, 32);
        q += __shfl_xor(q, 16); q += __shfl_xor(q, 32);
        float mu   = s * (1.f / 256.f);
        float rstd = rsqrtf(q * (1.f / 256.f) - mu * mu + 1e-5f);
        int ob = wid * 16 + quad * 4;
        #pragma unroll
        for (int r = 0; r < 4; ++r) {
            float y = (acc2[nt][r] - mu) * rstd * ((const float*)&gv)[r]
                      + ((const float*)&bv)[r];
            op[(size_t)(ob + r) * Nn + row] = y;
        }
    }
}

// ---------------------------------------------------------------------------
extern "C" void kernel_launch(void* const* d_in, const int* in_sizes, int n_in,
                              void* d_out, int out_size, void* d_ws, size_t ws_size,
                              hipStream_t stream) {
    const float* feature = (const float*)d_in[0];
    const float* bcw     = (const float*)d_in[1];
    const float* wq = (const float*)d_in[2];  const float* bq = (const float*)d_in[3];
    const float* wk = (const float*)d_in[4];  const float* bk = (const float*)d_in[5];
    const float* wv = (const float*)d_in[6];  const float* bv = (const float*)d_in[7];
    const float* wm = (const float*)d_in[8];  const float* bm = (const float*)d_in[9];
    const float* w1 = (const float*)d_in[10]; const float* b1 = (const float*)d_in[11];
    const float* w2 = (const float*)d_in[12]; const float* b2 = (const float*)d_in[13];
    const float* gm = (const float*)d_in[14]; const float* bt = (const float*)d_in[15];

    // workspace layout (~962 KB)
    float*  Kf32 = (float*)d_ws;             // 16384 f32
    float*  Vf32 = Kf32 + 16384;             // 16384 f32
    bf16_t* wqf  = (bf16_t*)(Vf32 + 16384);  // 65536 bf16
    bf16_t* wmf  = wqf + 65536;              // 65536
    bf16_t* w1f  = wmf + 65536;              // 131072
    bf16_t* w2f  = w1f + 131072;             // 131072
    bf16_t* Kf   = w2f + 131072;             // 16384
    bf16_t* Vf   = Kf + 16384;               // 16384
    float*  bqp  = (float*)(Vf + 16384);     // 256 f32

    float* op = (float*)d_out;

    hipLaunchKernelGGL(kv_kernel, dim3(Cc), dim3(Mm), 0, stream,
                       wk, bk, wv, bv, bcw, Kf32, Vf32);
    hipLaunchKernelGGL(pack_kernel, dim3((426240 + 255) / 256), dim3(256), 0, stream,
                       wq, bq, wm, w1, w2, Kf32, Vf32,
                       wqf, wmf, w1f, w2f, Kf, Vf, bqp);
    hipLaunchKernelGGL(sfta_mfma, dim3(NTB, Bc), dim3(1024), 0, stream,
                       feature, wqf, bqp, wmf, bm, w1f, b1, w2f, b2,
                       Kf, Vf, gm, bt, op);
}